// Round 5
// baseline (457.905 us; speedup 1.0000x reference)
//
#include <hip/hip_runtime.h>
#include <hip/hip_fp16.h>
#include <cstdint>

#define THREADS 256
#define NBLK 64     // blocks for hist/scatter
#define BPAD 512    // padded bucket count (dst>>8; N<=131072)

// ---------------- init ----------------
__global__ void init_kernel(float* pool, int* root, int G) {
  int i = blockIdx.x * blockDim.x + threadIdx.x;
  if (i < G * 64) pool[i] = 0.0f;
  if (i < G) root[i] = 0x7fffffff;
}

// ---------------- CSR build: bucket sort, no global atomics ----------------
__global__ __launch_bounds__(256) void hist_kernel(const int* __restrict__ dst_e,
                                                   int* __restrict__ hist, int E, int chunk) {
  __shared__ int hcnt[BPAD];
  int t = threadIdx.x, blk = blockIdx.x;
  for (int i = t; i < BPAD; i += 256) hcnt[i] = 0;
  __syncthreads();
  int s = blk * chunk, e = s + chunk;
  if (e > E) e = E;
  for (int i = s + t; i < e; i += 256) atomicAdd(&hcnt[dst_e[i] >> 8], 1);
  __syncthreads();
  for (int b = t; b < BPAD; b += 256) hist[b * NBLK + blk] = hcnt[b];
}

__global__ __launch_bounds__(256) void hscan_kernel(int* __restrict__ hist) {
  __shared__ int part[256];
  const int PER = (BPAD * NBLK) / 256;  // 128
  int t = threadIdx.x;
  int base = t * PER;
  int sum = 0;
  for (int k = 0; k < PER; k++) sum += hist[base + k];
  part[t] = sum;
  __syncthreads();
  int own = sum;
  for (int off = 1; off < 256; off <<= 1) {
    int v = (t >= off) ? part[t - off] : 0;
    __syncthreads();
    part[t] += v;
    __syncthreads();
  }
  int run = part[t] - own;
  for (int k = 0; k < PER; k++) {
    int h = hist[base + k];
    hist[base + k] = run;
    run += h;
  }
}

__global__ __launch_bounds__(256) void scatter_kernel(const int* __restrict__ src_e,
                                                      const int* __restrict__ dst_e,
                                                      const int* __restrict__ hist,
                                                      int2* __restrict__ ebuf, int E, int chunk) {
  __shared__ int cur[BPAD];
  int t = threadIdx.x, blk = blockIdx.x;
  for (int b = t; b < BPAD; b += 256) cur[b] = hist[b * NBLK + blk];
  __syncthreads();
  int s = blk * chunk, e = s + chunk;
  if (e > E) e = E;
  for (int i = s + t; i < e; i += 256) {
    int d = dst_e[i], sv = src_e[i];
    int slot = atomicAdd(&cur[d >> 8], 1);
    ebuf[slot] = make_int2(sv, d);
  }
}

// Pass 4: per-bucket CSR finalize: row_start + csr_src + local-dst byte.
__global__ __launch_bounds__(256) void build_kernel(const int2* __restrict__ ebuf,
                                                    const int* __restrict__ hist,
                                                    int* __restrict__ row_start,
                                                    int* __restrict__ csr_src,
                                                    unsigned char* __restrict__ dst8,
                                                    int N, int E) {
  __shared__ int counts[256];
  __shared__ int sc[256];
  __shared__ int curw[256];
  int t = threadIdx.x, b = blockIdx.x;
  int nbase = b * 256;
  int ebase = hist[b * NBLK];
  int eend = hist[(b + 1) * NBLK];
  counts[t] = 0;
  __syncthreads();
  int ecount = eend - ebase;
  for (int i = t; i < ecount; i += 256)
    atomicAdd(&counts[ebuf[ebase + i].y - nbase], 1);
  __syncthreads();
  int n = nbase + t;
  int val = (n < N) ? counts[t] + 1 : 0;  // +1 self-loop
  sc[t] = val;
  __syncthreads();
  int own = val;
  for (int off = 1; off < 256; off <<= 1) {
    int v = (t >= off) ? sc[t - off] : 0;
    __syncthreads();
    sc[t] += v;
    __syncthreads();
  }
  int myloc = sc[t] - own;  // exclusive
  int rowb = ebase + nbase;  // prior real edges + prior self-loops
  if (n < N) {
    row_start[n] = rowb + myloc;
    csr_src[rowb + myloc + counts[t]] = n;  // self-loop in last slot
    dst8[rowb + myloc + counts[t]] = (unsigned char)t;
    if (n == N - 1) row_start[N] = rowb + myloc + counts[t] + 1;
  }
  curw[t] = rowb + myloc;
  __syncthreads();
  for (int i = t; i < ecount; i += 256) {
    int2 ev = ebuf[ebase + i];
    int pos = atomicAdd(&curw[ev.y - nbase], 1);
    csr_src[pos] = ev.x;
    dst8[pos] = (unsigned char)(ev.y - nbase);
  }
}

// ---------------- linear + attention scalars ----------------
template <int K>
__global__ __launch_bounds__(256) void lin_attn_kernel(
    const float* __restrict__ in, const float* __restrict__ W,
    const float* __restrict__ a_src, const float* __restrict__ a_dst,
    __half2* __restrict__ h2, float* __restrict__ as_, float* __restrict__ ad_, int N) {
  constexpr int KP = K + 4;
  __shared__ float sW[K * 64];
  __shared__ float sIn[4][8][KP];
  const int t = threadIdx.x;
  const int lane = t & 63, w = t >> 6;
  const int cg = lane & 15, nl = lane >> 4;

  for (int i = t; i < K * 64; i += 256) sW[i] = W[i];

  const int nodeBase = blockIdx.x * 32 + w * 8;
  {
    const int nf4 = 8 * (K / 4);
    const float4* inv4 = (const float4*)(in + (size_t)nodeBase * K);
    for (int i = lane; i < nf4; i += 64) {
      int row = i / (K / 4), j = i % (K / 4);
      if (nodeBase + row < N) {
        float4 v = inv4[i];
        *(float4*)&sIn[w][row][j * 4] = v;
      }
    }
  }
  __syncthreads();

  float acc[2][4] = {{0.f, 0.f, 0.f, 0.f}, {0.f, 0.f, 0.f, 0.f}};
#pragma unroll 8
  for (int k = 0; k < K; k++) {
    float4 wv = *(const float4*)&sW[k * 64 + cg * 4];
    float i0 = sIn[w][nl][k];
    float i1 = sIn[w][nl + 4][k];
    acc[0][0] += i0 * wv.x; acc[0][1] += i0 * wv.y;
    acc[0][2] += i0 * wv.z; acc[0][3] += i0 * wv.w;
    acc[1][0] += i1 * wv.x; acc[1][1] += i1 * wv.y;
    acc[1][2] += i1 * wv.z; acc[1][3] += i1 * wv.w;
  }

  float4 av = *(const float4*)(a_src + cg * 4);
  float4 dv = *(const float4*)(a_dst + cg * 4);
#pragma unroll
  for (int p = 0; p < 2; p++) {
    int n = nodeBase + nl + p * 4;
    if (n < N) {
      __half2 p0 = __floats2half2_rn(acc[p][0], acc[p][1]);
      __half2 p1 = __floats2half2_rn(acc[p][2], acc[p][3]);
      h2[(size_t)n * 32 + cg * 2]     = p0;
      h2[(size_t)n * 32 + cg * 2 + 1] = p1;
      float ps = acc[p][0] * av.x + acc[p][1] * av.y + acc[p][2] * av.z + acc[p][3] * av.w;
      float pd = acc[p][0] * dv.x + acc[p][1] * dv.y + acc[p][2] * dv.z + acc[p][3] * dv.w;
      for (int m = 1; m < 16; m <<= 1) {
        ps += __shfl_xor(ps, m);
        pd += __shfl_xor(pd, m);
      }
      if (cg == 0) { as_[n] = ps; ad_[n] = pd; }
    }
  }
}

// ---------------- edge scores (edge-parallel, coalesced) ----------------
// coef[slot] = exp(leaky(as_[csr_src[slot]] + ad_[nbase + dst8[slot]]))
__global__ __launch_bounds__(256) void score_kernel(
    const float* __restrict__ as_, const float* __restrict__ ad_,
    const int* __restrict__ csr_src, const unsigned char* __restrict__ dst8,
    const int* __restrict__ row_start, float* __restrict__ coef, int N) {
  int b = blockIdx.x;
  int part = blockIdx.y;
  int nbase = b * 256;
  int nend = nbase + 256; if (nend > N) nend = N;
  int sBeg = row_start[nbase];
  int sEnd = row_start[nend];
  for (int s = sBeg + part * 256 + threadIdx.x; s < sEnd; s += 1024) {
    int src = csr_src[s];
    float e = as_[src] + ad_[nbase + dst8[s]];
    e = (e > 0.f) ? e : 0.2f * e;
    coef[s] = __expf(e);
  }
}

// ---------------- aggregation: out[n] = relu(sum coef*h[src]/den + b) -------
// wave per node; lane = g*8+co: g = edge-in-group-of-8, co = channel octet.
// Each lane: ONE dwordx4 gather (8 fp16 channels) per 8 edges; coef/src
// broadcast through the load unit (8 lanes share the address).
__global__ __launch_bounds__(256) void agg_kernel(
    const __half2* __restrict__ h2, const float* __restrict__ coef,
    const int* __restrict__ csr_src, const int* __restrict__ row_start,
    const float* __restrict__ b, float* __restrict__ out, int N) {
  int t = threadIdx.x;
  int lane = t & 63, w = t >> 6;
  int n = blockIdx.x * 4 + w;
  if (n >= N) return;
  int rs = row_start[n], re = row_start[n + 1];
  int g = lane >> 3, co = lane & 7;

  float den = 0.f;
  for (int s = rs + lane; s < re; s += 64) den += coef[s];
#pragma unroll
  for (int k = 1; k < 64; k <<= 1) den += __shfl_xor(den, k);

  float4 A0 = make_float4(0.f, 0.f, 0.f, 0.f);
  float4 A1 = make_float4(0.f, 0.f, 0.f, 0.f);
  const float4* h4 = (const float4*)h2;  // 8 float4 (=128B) per node row
  for (int base = rs; base < re; base += 8) {
    int sl = base + g;
    int slc = (sl < re) ? sl : (re - 1);
    float cf = coef[slc];
    if (sl >= re) cf = 0.f;
    int src = csr_src[slc];
    float4 hv = h4[(size_t)src * 8 + co];
    const __half2* hp = (const __half2*)&hv;
    float2 f0 = __half22float2(hp[0]);
    float2 f1 = __half22float2(hp[1]);
    float2 f2 = __half22float2(hp[2]);
    float2 f3 = __half22float2(hp[3]);
    A0.x += cf * f0.x; A0.y += cf * f0.y; A0.z += cf * f1.x; A0.w += cf * f1.y;
    A1.x += cf * f2.x; A1.y += cf * f2.y; A1.z += cf * f3.x; A1.w += cf * f3.y;
  }
#pragma unroll
  for (int k = 8; k < 64; k <<= 1) {
    A0.x += __shfl_xor(A0.x, k); A0.y += __shfl_xor(A0.y, k);
    A0.z += __shfl_xor(A0.z, k); A0.w += __shfl_xor(A0.w, k);
    A1.x += __shfl_xor(A1.x, k); A1.y += __shfl_xor(A1.y, k);
    A1.z += __shfl_xor(A1.z, k); A1.w += __shfl_xor(A1.w, k);
  }
  if (g == 0) {
    float inv = 1.0f / (den + 1e-16f);
    float4 b0 = *(const float4*)&b[co * 8];
    float4 b1 = *(const float4*)&b[co * 8 + 4];
    float4 o0, o1;
    o0.x = fmaxf(A0.x * inv + b0.x, 0.f);
    o0.y = fmaxf(A0.y * inv + b0.y, 0.f);
    o0.z = fmaxf(A0.z * inv + b0.z, 0.f);
    o0.w = fmaxf(A0.w * inv + b0.w, 0.f);
    o1.x = fmaxf(A1.x * inv + b1.x, 0.f);
    o1.y = fmaxf(A1.y * inv + b1.y, 0.f);
    o1.z = fmaxf(A1.z * inv + b1.z, 0.f);
    o1.w = fmaxf(A1.w * inv + b1.w, 0.f);
    *(float4*)&out[(size_t)n * 64 + co * 8] = o0;
    *(float4*)&out[(size_t)n * 64 + co * 8 + 4] = o1;
  }
}

// ---------------- global max pool + root detection ----------------
__global__ void pool_kernel(const float* __restrict__ h, const int* __restrict__ batch,
                            float* __restrict__ pool, int* __restrict__ root,
                            int N, int chunk) {
  int t = threadIdx.x;
  int lane = t & 63, w = t >> 6;
  int row = blockIdx.x * 4 + w;
  int start = row * chunk;
  if (start >= N) return;
  int end = start + chunk; if (end > N) end = N;
  int cur_g = batch[start];
  if (lane == 0 && (start == 0 || batch[start - 1] != cur_g)) atomicMin(&root[cur_g], start);
  float rm = 0.0f;  // h >= 0 (post-relu), pool init 0
  for (int n = start; n < end; n++) {
    int g = batch[n];
    if (g != cur_g) {
      atomicMax((int*)&pool[(size_t)cur_g * 64 + lane], __float_as_int(rm));
      if (lane == 0) atomicMin(&root[g], n);
      cur_g = g;
      rm = 0.0f;
    }
    rm = fmaxf(rm, h[(size_t)n * 64 + lane]);
  }
  atomicMax((int*)&pool[(size_t)cur_g * 64 + lane], __float_as_int(rm));
}

// ---------------- final fused MLP head (wave per graph) ----------------
__global__ void final_kernel(const float* __restrict__ pool, const int* __restrict__ root,
                             const float* __restrict__ x,
                             const float* __restrict__ lin0_W, const float* __restrict__ lin0_b,
                             const float* __restrict__ linnews_W, const float* __restrict__ linnews_b,
                             const float* __restrict__ lin1_W, const float* __restrict__ lin1_b,
                             float* __restrict__ out, int G, int N) {
  int t = threadIdx.x;
  int lane = t & 63, w = t >> 6;
  int g = blockIdx.x * 4 + w;
  if (g >= G) return;
  float hp = 0.f;
  for (int k = 0; k < 64; k++) hp += pool[(size_t)g * 64 + k] * lin0_W[k * 64 + lane];
  hp = fmaxf(hp + lin0_b[lane], 0.f);
  int r = root[g]; if (r > N - 1) r = N - 1; if (r < 0) r = 0;
  float nw = 0.f;
  for (int k = 0; k < 128; k++) nw += x[(size_t)r * 128 + k] * linnews_W[k * 64 + lane];
  nw = fmaxf(nw + linnews_b[lane], 0.f);
  float p = hp * lin1_W[lane] + nw * lin1_W[64 + lane];
  for (int k = 1; k < 64; k <<= 1) p += __shfl_xor(p, k);
  if (lane == 0) out[g] = 1.0f / (1.0f + __expf(-(p + lin1_b[0])));
}

// ---------------- launch ----------------
extern "C" void kernel_launch(void* const* d_in, const int* in_sizes, int n_in,
                              void* d_out, int out_size, void* d_ws, size_t ws_size,
                              hipStream_t stream) {
  (void)n_in; (void)ws_size;
  const float* x      = (const float*)d_in[0];
  const int*   adj    = (const int*)d_in[1];
  const int*   batch  = (const int*)d_in[2];
  const float* W1     = (const float*)d_in[3];
  const float* asrc1  = (const float*)d_in[4];
  const float* adst1  = (const float*)d_in[5];
  const float* b1     = (const float*)d_in[6];
  const float* W2     = (const float*)d_in[7];
  const float* asrc2  = (const float*)d_in[8];
  const float* adst2  = (const float*)d_in[9];
  const float* b2     = (const float*)d_in[10];
  const float* W3     = (const float*)d_in[11];
  const float* asrc3  = (const float*)d_in[12];
  const float* adst3  = (const float*)d_in[13];
  const float* b3     = (const float*)d_in[14];
  const float* lnW    = (const float*)d_in[15];
  const float* lnb    = (const float*)d_in[16];
  const float* l0W    = (const float*)d_in[17];
  const float* l0b    = (const float*)d_in[18];
  const float* l1W    = (const float*)d_in[19];
  const float* l1b    = (const float*)d_in[20];
  float* outp = (float*)d_out;

  const int N = in_sizes[2];
  const int E = in_sizes[1] / 2;
  const int Etot = E + N;
  const int G = out_size;
  const int B = (N + 255) / 256;  // real buckets (<= BPAD)

  const int* src_e = adj;
  const int* dst_e = adj + E;

  uintptr_t p = (uintptr_t)d_ws;
  auto alloc = [&](size_t bytes) -> void* {
    void* r = (void*)p;
    p += (bytes + 255) & ~(size_t)255;
    return r;
  };
  int*     hist      = (int*)alloc((size_t)BPAD * NBLK * 4);
  int*     row_start = (int*)alloc((size_t)(N + 1) * 4);
  int*     csr_src   = (int*)alloc((size_t)Etot * 4);
  unsigned char* dst8 = (unsigned char*)alloc((size_t)Etot);
  float*   coef      = (float*)alloc((size_t)Etot * 4);
  int2*    ebuf      = (int2*)alloc((size_t)E * 8);
  __half2* h2        = (__half2*)alloc((size_t)N * 32 * 4);
  float*   bufA      = (float*)alloc((size_t)N * 64 * 4);
  float*   as_       = (float*)alloc((size_t)N * 4);
  float*   ad_       = (float*)alloc((size_t)N * 4);
  float*   pool      = (float*)alloc((size_t)G * 64 * 4);
  int*     root      = (int*)alloc((size_t)G * 4);

  init_kernel<<<dim3((G * 64 + THREADS - 1) / THREADS), dim3(THREADS), 0, stream>>>(pool, root, G);

  int chunk = (E + NBLK - 1) / NBLK;
  hist_kernel<<<dim3(NBLK), dim3(256), 0, stream>>>(dst_e, hist, E, chunk);
  hscan_kernel<<<dim3(1), dim3(256), 0, stream>>>(hist);
  scatter_kernel<<<dim3(NBLK), dim3(256), 0, stream>>>(src_e, dst_e, hist, ebuf, E, chunk);
  build_kernel<<<dim3(B), dim3(256), 0, stream>>>(ebuf, hist, row_start, csr_src, dst8, N, E);

  const int linGrid = (N + 31) / 32;
  const int aggGrid = (N + 3) / 4;
  dim3 scoreGrid(B, 4);

  // layer 1
  lin_attn_kernel<128><<<dim3(linGrid), dim3(256), 0, stream>>>(x, W1, asrc1, adst1, h2, as_, ad_, N);
  score_kernel<<<scoreGrid, dim3(256), 0, stream>>>(as_, ad_, csr_src, dst8, row_start, coef, N);
  agg_kernel<<<dim3(aggGrid), dim3(256), 0, stream>>>(h2, coef, csr_src, row_start, b1, bufA, N);
  // layer 2
  lin_attn_kernel<64><<<dim3(linGrid), dim3(256), 0, stream>>>(bufA, W2, asrc2, adst2, h2, as_, ad_, N);
  score_kernel<<<scoreGrid, dim3(256), 0, stream>>>(as_, ad_, csr_src, dst8, row_start, coef, N);
  agg_kernel<<<dim3(aggGrid), dim3(256), 0, stream>>>(h2, coef, csr_src, row_start, b2, bufA, N);
  // layer 3
  lin_attn_kernel<64><<<dim3(linGrid), dim3(256), 0, stream>>>(bufA, W3, asrc3, adst3, h2, as_, ad_, N);
  score_kernel<<<scoreGrid, dim3(256), 0, stream>>>(as_, ad_, csr_src, dst8, row_start, coef, N);
  agg_kernel<<<dim3(aggGrid), dim3(256), 0, stream>>>(h2, coef, csr_src, row_start, b3, bufA, N);

  // pool + root
  const int ROWS = 2048;
  int pchunk = (N + ROWS - 1) / ROWS;
  pool_kernel<<<dim3(ROWS / 4), dim3(256), 0, stream>>>(bufA, batch, pool, root, N, pchunk);

  // head
  final_kernel<<<dim3((G + 3) / 4), dim3(256), 0, stream>>>(
      pool, root, x, l0W, l0b, lnW, lnb, l1W, l1b, outp, G, N);
}

// Round 6
// 387.117 us; speedup vs baseline: 1.1829x; 1.1829x over previous
//
#include <hip/hip_runtime.h>
#include <hip/hip_fp16.h>
#include <cstdint>

#define THREADS 256
#define NBLK 64     // blocks for hist/scatter
#define BPAD 512    // padded bucket count (dst>>8; N<=131072)

// ---------------- init ----------------
__global__ void init_kernel(float* pool, int* root, int G) {
  int i = blockIdx.x * blockDim.x + threadIdx.x;
  if (i < G * 64) pool[i] = 0.0f;
  if (i < G) root[i] = 0x7fffffff;
}

// ---------------- CSR build: bucket sort, no global atomics ----------------
__global__ __launch_bounds__(256) void hist_kernel(const int* __restrict__ dst_e,
                                                   int* __restrict__ hist, int E, int chunk) {
  __shared__ int hcnt[BPAD];
  int t = threadIdx.x, blk = blockIdx.x;
  for (int i = t; i < BPAD; i += 256) hcnt[i] = 0;
  __syncthreads();
  int s = blk * chunk, e = s + chunk;
  if (e > E) e = E;
  for (int i = s + t; i < e; i += 256) atomicAdd(&hcnt[dst_e[i] >> 8], 1);
  __syncthreads();
  for (int b = t; b < BPAD; b += 256) hist[b * NBLK + blk] = hcnt[b];
}

__global__ __launch_bounds__(256) void hscan_kernel(int* __restrict__ hist) {
  __shared__ int part[256];
  const int PER = (BPAD * NBLK) / 256;  // 128
  int t = threadIdx.x;
  int base = t * PER;
  int sum = 0;
  for (int k = 0; k < PER; k++) sum += hist[base + k];
  part[t] = sum;
  __syncthreads();
  int own = sum;
  for (int off = 1; off < 256; off <<= 1) {
    int v = (t >= off) ? part[t - off] : 0;
    __syncthreads();
    part[t] += v;
    __syncthreads();
  }
  int run = part[t] - own;
  for (int k = 0; k < PER; k++) {
    int h = hist[base + k];
    hist[base + k] = run;
    run += h;
  }
}

// scatter edges into bucket-partitioned ebuf, packed (src<<8)|(dst&255).
__global__ __launch_bounds__(256) void scatter_kernel(const int* __restrict__ src_e,
                                                      const int* __restrict__ dst_e,
                                                      const int* __restrict__ hist,
                                                      unsigned int* __restrict__ ebuf,
                                                      int E, int chunk) {
  __shared__ int cur[BPAD];
  int t = threadIdx.x, blk = blockIdx.x;
  for (int b = t; b < BPAD; b += 256) cur[b] = hist[b * NBLK + blk];
  __syncthreads();
  int s = blk * chunk, e = s + chunk;
  if (e > E) e = E;
  for (int i = s + t; i < e; i += 256) {
    int d = dst_e[i];
    unsigned int sv = (unsigned int)src_e[i];
    int slot = atomicAdd(&cur[d >> 8], 1);
    ebuf[slot] = (sv << 8) | (unsigned int)(d & 255);
  }
}

// per-bucket CSR finalize: row_start + csr_src + local-dst byte.
__global__ __launch_bounds__(256) void build_kernel(const unsigned int* __restrict__ ebuf,
                                                    const int* __restrict__ hist,
                                                    int* __restrict__ row_start,
                                                    int* __restrict__ csr_src,
                                                    unsigned char* __restrict__ dst8,
                                                    int N, int E) {
  __shared__ int counts[256];
  __shared__ int sc[256];
  __shared__ int curw[256];
  int t = threadIdx.x, b = blockIdx.x;
  int nbase = b * 256;
  int ebase = hist[b * NBLK];
  int eend = hist[(b + 1) * NBLK];
  counts[t] = 0;
  __syncthreads();
  int ecount = eend - ebase;
  for (int i = t; i < ecount; i += 256)
    atomicAdd(&counts[ebuf[ebase + i] & 255u], 1);
  __syncthreads();
  int n = nbase + t;
  int val = (n < N) ? counts[t] + 1 : 0;  // +1 self-loop
  sc[t] = val;
  __syncthreads();
  int own = val;
  for (int off = 1; off < 256; off <<= 1) {
    int v = (t >= off) ? sc[t - off] : 0;
    __syncthreads();
    sc[t] += v;
    __syncthreads();
  }
  int myloc = sc[t] - own;  // exclusive
  int rowb = ebase + nbase;  // prior real edges + prior self-loops
  if (n < N) {
    row_start[n] = rowb + myloc;
    csr_src[rowb + myloc + counts[t]] = n;  // self-loop in last slot
    dst8[rowb + myloc + counts[t]] = (unsigned char)t;
    if (n == N - 1) row_start[N] = rowb + myloc + counts[t] + 1;
  }
  curw[t] = rowb + myloc;
  __syncthreads();
  for (int i = t; i < ecount; i += 256) {
    unsigned int ev = ebuf[ebase + i];
    int ld = (int)(ev & 255u);
    int pos = atomicAdd(&curw[ld], 1);
    csr_src[pos] = (int)(ev >> 8);
    dst8[pos] = (unsigned char)ld;
  }
}

// ---------------- linear + attention scalars ----------------
template <int K>
__global__ __launch_bounds__(256) void lin_attn_kernel(
    const float* __restrict__ in, const float* __restrict__ W,
    const float* __restrict__ a_src, const float* __restrict__ a_dst,
    __half2* __restrict__ h2, float* __restrict__ as_, float* __restrict__ ad_, int N) {
  constexpr int KP = K + 4;
  __shared__ float sW[K * 64];
  __shared__ float sIn[4][8][KP];
  const int t = threadIdx.x;
  const int lane = t & 63, w = t >> 6;
  const int cg = lane & 15, nl = lane >> 4;

  for (int i = t; i < K * 64; i += 256) sW[i] = W[i];

  const int nodeBase = blockIdx.x * 32 + w * 8;
  {
    const int nf4 = 8 * (K / 4);
    const float4* inv4 = (const float4*)(in + (size_t)nodeBase * K);
    for (int i = lane; i < nf4; i += 64) {
      int row = i / (K / 4), j = i % (K / 4);
      if (nodeBase + row < N) {
        float4 v = inv4[i];
        *(float4*)&sIn[w][row][j * 4] = v;
      }
    }
  }
  __syncthreads();

  float acc[2][4] = {{0.f, 0.f, 0.f, 0.f}, {0.f, 0.f, 0.f, 0.f}};
#pragma unroll 8
  for (int k = 0; k < K; k++) {
    float4 wv = *(const float4*)&sW[k * 64 + cg * 4];
    float i0 = sIn[w][nl][k];
    float i1 = sIn[w][nl + 4][k];
    acc[0][0] += i0 * wv.x; acc[0][1] += i0 * wv.y;
    acc[0][2] += i0 * wv.z; acc[0][3] += i0 * wv.w;
    acc[1][0] += i1 * wv.x; acc[1][1] += i1 * wv.y;
    acc[1][2] += i1 * wv.z; acc[1][3] += i1 * wv.w;
  }

  float4 av = *(const float4*)(a_src + cg * 4);
  float4 dv = *(const float4*)(a_dst + cg * 4);
#pragma unroll
  for (int p = 0; p < 2; p++) {
    int n = nodeBase + nl + p * 4;
    if (n < N) {
      __half2 p0 = __floats2half2_rn(acc[p][0], acc[p][1]);
      __half2 p1 = __floats2half2_rn(acc[p][2], acc[p][3]);
      h2[(size_t)n * 32 + cg * 2]     = p0;
      h2[(size_t)n * 32 + cg * 2 + 1] = p1;
      float ps = acc[p][0] * av.x + acc[p][1] * av.y + acc[p][2] * av.z + acc[p][3] * av.w;
      float pd = acc[p][0] * dv.x + acc[p][1] * dv.y + acc[p][2] * dv.z + acc[p][3] * dv.w;
      for (int m = 1; m < 16; m <<= 1) {
        ps += __shfl_xor(ps, m);
        pd += __shfl_xor(pd, m);
      }
      if (cg == 0) { as_[n] = ps; ad_[n] = pd; }
    }
  }
}

// ---------------- edge scores (edge-parallel, coalesced) ----------------
__global__ __launch_bounds__(256) void score_kernel(
    const float* __restrict__ as_, const float* __restrict__ ad_,
    const int* __restrict__ csr_src, const unsigned char* __restrict__ dst8,
    const int* __restrict__ row_start, float* __restrict__ coef, int N) {
  int b = blockIdx.x;
  int part = blockIdx.y;
  int nbase = b * 256;
  int nend = nbase + 256; if (nend > N) nend = N;
  int sBeg = row_start[nbase];
  int sEnd = row_start[nend];
  for (int s = sBeg + part * 256 + threadIdx.x; s < sEnd; s += 1024) {
    int src = csr_src[s];
    float e = as_[src] + ad_[nbase + dst8[s]];
    e = (e > 0.f) ? e : 0.2f * e;
    coef[s] = __expf(e);
  }
}

// ---------------- aggregation: out[n] = relu(sum coef*h[src]/den + b) -------
// 8 lanes per node (8 nodes/wave); lane co = channel octet OWNS its 8
// channels across all edges -> zero cross-lane reductions. coef/csr loads are
// 8-lane broadcast; den accumulates redundantly per lane. 4-way unrolled
// edge loop keeps 4 independent 16B gathers in flight per lane.
__global__ __launch_bounds__(256) void agg_kernel(
    const __half2* __restrict__ h2, const float* __restrict__ coef,
    const int* __restrict__ csr_src, const int* __restrict__ row_start,
    const float* __restrict__ b, float* __restrict__ out, int N) {
  int t = threadIdx.x;
  int lane = t & 63, w = t >> 6;
  int ng = lane >> 3, co = lane & 7;
  int n = blockIdx.x * 32 + w * 8 + ng;
  if (n >= N) return;
  int rs = row_start[n], re = row_start[n + 1];
  const float4* h4 = (const float4*)h2;  // 8 float4 (=128B) per node row

  float4 A0 = make_float4(0.f, 0.f, 0.f, 0.f);
  float4 A1 = make_float4(0.f, 0.f, 0.f, 0.f);
  float den = 0.f;
  for (int s = rs; s < re; s += 4) {
    float cf[4];
    int src[4];
#pragma unroll
    for (int j = 0; j < 4; j++) {
      int sj = s + j;
      int sc = (sj < re) ? sj : (re - 1);
      cf[j] = coef[sc];
      if (sj >= re) cf[j] = 0.f;
      src[j] = csr_src[sc];
    }
#pragma unroll
    for (int j = 0; j < 4; j++) {
      float4 hv = h4[(size_t)src[j] * 8 + co];
      const __half2* hp = (const __half2*)&hv;
      float2 f0 = __half22float2(hp[0]);
      float2 f1 = __half22float2(hp[1]);
      float2 f2 = __half22float2(hp[2]);
      float2 f3 = __half22float2(hp[3]);
      float c = cf[j];
      den += c;
      A0.x += c * f0.x; A0.y += c * f0.y; A0.z += c * f1.x; A0.w += c * f1.y;
      A1.x += c * f2.x; A1.y += c * f2.y; A1.z += c * f3.x; A1.w += c * f3.y;
    }
  }
  float inv = 1.0f / (den + 1e-16f);
  float4 b0 = *(const float4*)&b[co * 8];
  float4 b1 = *(const float4*)&b[co * 8 + 4];
  float4 o0, o1;
  o0.x = fmaxf(A0.x * inv + b0.x, 0.f);
  o0.y = fmaxf(A0.y * inv + b0.y, 0.f);
  o0.z = fmaxf(A0.z * inv + b0.z, 0.f);
  o0.w = fmaxf(A0.w * inv + b0.w, 0.f);
  o1.x = fmaxf(A1.x * inv + b1.x, 0.f);
  o1.y = fmaxf(A1.y * inv + b1.y, 0.f);
  o1.z = fmaxf(A1.z * inv + b1.z, 0.f);
  o1.w = fmaxf(A1.w * inv + b1.w, 0.f);
  *(float4*)&out[(size_t)n * 64 + co * 8] = o0;
  *(float4*)&out[(size_t)n * 64 + co * 8 + 4] = o1;
}

// ---------------- global max pool + root detection ----------------
__global__ void pool_kernel(const float* __restrict__ h, const int* __restrict__ batch,
                            float* __restrict__ pool, int* __restrict__ root,
                            int N, int chunk) {
  int t = threadIdx.x;
  int lane = t & 63, w = t >> 6;
  int row = blockIdx.x * 4 + w;
  int start = row * chunk;
  if (start >= N) return;
  int end = start + chunk; if (end > N) end = N;
  int cur_g = batch[start];
  if (lane == 0 && (start == 0 || batch[start - 1] != cur_g)) atomicMin(&root[cur_g], start);
  float rm = 0.0f;  // h >= 0 (post-relu), pool init 0
  for (int n = start; n < end; n++) {
    int g = batch[n];
    if (g != cur_g) {
      atomicMax((int*)&pool[(size_t)cur_g * 64 + lane], __float_as_int(rm));
      if (lane == 0) atomicMin(&root[g], n);
      cur_g = g;
      rm = 0.0f;
    }
    rm = fmaxf(rm, h[(size_t)n * 64 + lane]);
  }
  atomicMax((int*)&pool[(size_t)cur_g * 64 + lane], __float_as_int(rm));
}

// ---------------- final fused MLP head (wave per graph) ----------------
__global__ void final_kernel(const float* __restrict__ pool, const int* __restrict__ root,
                             const float* __restrict__ x,
                             const float* __restrict__ lin0_W, const float* __restrict__ lin0_b,
                             const float* __restrict__ linnews_W, const float* __restrict__ linnews_b,
                             const float* __restrict__ lin1_W, const float* __restrict__ lin1_b,
                             float* __restrict__ out, int G, int N) {
  int t = threadIdx.x;
  int lane = t & 63, w = t >> 6;
  int g = blockIdx.x * 4 + w;
  if (g >= G) return;
  float hp = 0.f;
  for (int k = 0; k < 64; k++) hp += pool[(size_t)g * 64 + k] * lin0_W[k * 64 + lane];
  hp = fmaxf(hp + lin0_b[lane], 0.f);
  int r = root[g]; if (r > N - 1) r = N - 1; if (r < 0) r = 0;
  float nw = 0.f;
  for (int k = 0; k < 128; k++) nw += x[(size_t)r * 128 + k] * linnews_W[k * 64 + lane];
  nw = fmaxf(nw + linnews_b[lane], 0.f);
  float p = hp * lin1_W[lane] + nw * lin1_W[64 + lane];
  for (int k = 1; k < 64; k <<= 1) p += __shfl_xor(p, k);
  if (lane == 0) out[g] = 1.0f / (1.0f + __expf(-(p + lin1_b[0])));
}

// ---------------- launch ----------------
extern "C" void kernel_launch(void* const* d_in, const int* in_sizes, int n_in,
                              void* d_out, int out_size, void* d_ws, size_t ws_size,
                              hipStream_t stream) {
  (void)n_in; (void)ws_size;
  const float* x      = (const float*)d_in[0];
  const int*   adj    = (const int*)d_in[1];
  const int*   batch  = (const int*)d_in[2];
  const float* W1     = (const float*)d_in[3];
  const float* asrc1  = (const float*)d_in[4];
  const float* adst1  = (const float*)d_in[5];
  const float* b1     = (const float*)d_in[6];
  const float* W2     = (const float*)d_in[7];
  const float* asrc2  = (const float*)d_in[8];
  const float* adst2  = (const float*)d_in[9];
  const float* b2     = (const float*)d_in[10];
  const float* W3     = (const float*)d_in[11];
  const float* asrc3  = (const float*)d_in[12];
  const float* adst3  = (const float*)d_in[13];
  const float* b3     = (const float*)d_in[14];
  const float* lnW    = (const float*)d_in[15];
  const float* lnb    = (const float*)d_in[16];
  const float* l0W    = (const float*)d_in[17];
  const float* l0b    = (const float*)d_in[18];
  const float* l1W    = (const float*)d_in[19];
  const float* l1b    = (const float*)d_in[20];
  float* outp = (float*)d_out;

  const int N = in_sizes[2];
  const int E = in_sizes[1] / 2;
  const int Etot = E + N;
  const int G = out_size;
  const int B = (N + 255) / 256;  // real buckets (<= BPAD)

  const int* src_e = adj;
  const int* dst_e = adj + E;

  uintptr_t p = (uintptr_t)d_ws;
  auto alloc = [&](size_t bytes) -> void* {
    void* r = (void*)p;
    p += (bytes + 255) & ~(size_t)255;
    return r;
  };
  int*     hist      = (int*)alloc((size_t)BPAD * NBLK * 4);
  int*     row_start = (int*)alloc((size_t)(N + 1) * 4);
  int*     csr_src   = (int*)alloc((size_t)Etot * 4);
  unsigned char* dst8 = (unsigned char*)alloc((size_t)Etot);
  float*   coef      = (float*)alloc((size_t)Etot * 4);
  unsigned int* ebuf = (unsigned int*)alloc((size_t)E * 4);
  __half2* h2        = (__half2*)alloc((size_t)N * 32 * 4);
  float*   bufA      = (float*)alloc((size_t)N * 64 * 4);
  float*   as_       = (float*)alloc((size_t)N * 4);
  float*   ad_       = (float*)alloc((size_t)N * 4);
  float*   pool      = (float*)alloc((size_t)G * 64 * 4);
  int*     root      = (int*)alloc((size_t)G * 4);

  init_kernel<<<dim3((G * 64 + THREADS - 1) / THREADS), dim3(THREADS), 0, stream>>>(pool, root, G);

  int chunk = (E + NBLK - 1) / NBLK;
  hist_kernel<<<dim3(NBLK), dim3(256), 0, stream>>>(dst_e, hist, E, chunk);
  hscan_kernel<<<dim3(1), dim3(256), 0, stream>>>(hist);
  scatter_kernel<<<dim3(NBLK), dim3(256), 0, stream>>>(src_e, dst_e, hist, ebuf, E, chunk);
  build_kernel<<<dim3(B), dim3(256), 0, stream>>>(ebuf, hist, row_start, csr_src, dst8, N, E);

  const int linGrid = (N + 31) / 32;
  const int aggGrid = (N + 31) / 32;
  dim3 scoreGrid(B, 4);

  // layer 1
  lin_attn_kernel<128><<<dim3(linGrid), dim3(256), 0, stream>>>(x, W1, asrc1, adst1, h2, as_, ad_, N);
  score_kernel<<<scoreGrid, dim3(256), 0, stream>>>(as_, ad_, csr_src, dst8, row_start, coef, N);
  agg_kernel<<<dim3(aggGrid), dim3(256), 0, stream>>>(h2, coef, csr_src, row_start, b1, bufA, N);
  // layer 2
  lin_attn_kernel<64><<<dim3(linGrid), dim3(256), 0, stream>>>(bufA, W2, asrc2, adst2, h2, as_, ad_, N);
  score_kernel<<<scoreGrid, dim3(256), 0, stream>>>(as_, ad_, csr_src, dst8, row_start, coef, N);
  agg_kernel<<<dim3(aggGrid), dim3(256), 0, stream>>>(h2, coef, csr_src, row_start, b2, bufA, N);
  // layer 3
  lin_attn_kernel<64><<<dim3(linGrid), dim3(256), 0, stream>>>(bufA, W3, asrc3, adst3, h2, as_, ad_, N);
  score_kernel<<<scoreGrid, dim3(256), 0, stream>>>(as_, ad_, csr_src, dst8, row_start, coef, N);
  agg_kernel<<<dim3(aggGrid), dim3(256), 0, stream>>>(h2, coef, csr_src, row_start, b3, bufA, N);

  // pool + root
  const int ROWS = 2048;
  int pchunk = (N + ROWS - 1) / ROWS;
  pool_kernel<<<dim3(ROWS / 4), dim3(256), 0, stream>>>(bufA, batch, pool, root, N, pchunk);

  // head
  final_kernel<<<dim3((G + 3) / 4), dim3(256), 0, stream>>>(
      pool, root, x, l0W, l0b, lnW, lnb, l1W, l1b, outp, G, N);
}